// Round 14
// baseline (203.869 us; speedup 1.0000x reference)
//
#include <hip/hip_runtime.h>
#include <cstdint>

#define HW 3136
#define WID 56
#define NBLK 1792   // 32 frame-pairs * 56 rows

typedef float f4v __attribute__((ext_vector_type(4)));

__device__ __forceinline__ int clampi(int v, int lo, int hi) {
    return v < lo ? lo : (v > hi ? hi : v);
}
__device__ __forceinline__ uint32_t rne16(float f) {   // fp32 -> bf16 (RNE)
    uint32_t b = __float_as_uint(f);
    return (b + 0x7fffu + ((b >> 16) & 1u)) >> 16;
}
__device__ __forceinline__ float blo(uint32_t u) { return __uint_as_float(u << 16); }
__device__ __forceinline__ float bhi(uint32_t u) { return __uint_as_float(u & 0xffff0000u); }
__device__ __forceinline__ uint32_t bpermu(int a4, uint32_t v) {
    return (uint32_t)__builtin_amdgcn_ds_bpermute(a4, (int)v);
}
__device__ __forceinline__ float bperm(int a4, float v) {
    return __int_as_float(__builtin_amdgcn_ds_bpermute(a4, __float_as_int(v)));
}
__device__ __forceinline__ void fma2(float2& a, const float2& u, const float2& w) {
    a.x += u.x * w.x; a.y += u.y * w.y;
}

// ---------- pass A: stream x (fp32, NT loads: no L3 alloc) -> packed bf16
// pairs xb[pair][ch][px] = bf16(even) | bf16(odd)<<16 (normal stores -> L3).
__global__ __launch_bounds__(256) void tf_pack(const float* __restrict__ x,
                                               uint32_t* __restrict__ xb)
{
    const unsigned total4 = 8192u * 784u;   // (32 pair * 256 ch) planes * 784 quads
    unsigned i = blockIdx.x * 256u + threadIdx.x;
    const unsigned stride = gridDim.x * 256u;
    for (; i < total4; i += stride) {
        const unsigned p4 = i / 784u;          // plane = pair*256 + ch
        const unsigned i4 = i - p4 * 784u;
        const unsigned pair = p4 >> 8;
        const size_t eoff = ((size_t)pair * 512 + (p4 & 255u)) * HW + i4 * 4;
        const f4v e = __builtin_nontemporal_load((const f4v*)(x + eoff));
        const f4v o = __builtin_nontemporal_load((const f4v*)(x + eoff + (size_t)256 * HW));
        uint4 u;
        u.x = (rne16(o.x) << 16) | rne16(e.x);
        u.y = (rne16(o.y) << 16) | rne16(e.y);
        u.z = (rne16(o.z) << 16) | rne16(e.z);
        u.w = (rne16(o.w) << 16) | rne16(e.w);
        *(uint4*)(xb + (size_t)p4 * HW + i4 * 4) = u;
    }
}

// ---------- pass B: fused corr -> W -> gather, all x-taps from L3-resident xb.
// Block = 1 output row (56 px); 4 waves; wave su owns channels {2su,2su+1} of
// each 8-ch chunk. One b32 tap = both frames. LDS = CP 4032 + CR 16128 =
// 20160 B -> 8 blocks/CU. (256,2): the only non-spilling register config.
__global__ __launch_bounds__(256, 2) void tf_fused_bf(
    const uint32_t* __restrict__ xb, const float* __restrict__ wconv,
    const float* __restrict__ bconv, float* __restrict__ out)
{
    __shared__ float CP[2 * 9 * 56];   // 4032 B (2-slot reduce)
    __shared__ float CR[72 * 56];      // 16128 B

    const int d = blockIdx.x;
    const int logical = (d & 7) * 224 + (d >> 3);   // XCD-contiguous rows
    const int n  = logical / 56;
    const int r0 = logical % 56;
    const int t = threadIdx.x;
    const int su = __builtin_amdgcn_readfirstlane(t >> 6);
    const int lane = t & 63;
    const bool act = lane < WID;
    const int px = act ? lane : 55;

    const uint32_t* xq = xb + (size_t)n * 256 * HW;

    const int am = clampi(lane - 1, 0, 55) * 4;   // edge clamp folded in
    const int ap = clampi(lane + 1, 0, 55) * 4;

    const int rb0 = clampi(r0 - 1, 0, 55) * WID + px;
    const int rb1 = r0 * WID + px;
    const int rb2 = clampi(r0 + 1, 0, 55) * WID + px;

    // ================= phase 1: corr -> CR =================
    for (int g = 0; g < 8; ++g) {
        float crg[9];
        #pragma unroll
        for (int i = 0; i < 9; ++i) crg[i] = 0.f;

        #pragma unroll
        for (int sub = 0; sub < 4; ++sub) {
            const int ch0 = (g * 4 + sub) * 8 + 2 * su;
            #pragma unroll
            for (int c = 0; c < 2; ++c) {
                const uint32_t* base = xq + (size_t)(ch0 + c) * HW;
                const uint32_t u0 = base[rb0], u1 = base[rb1], u2 = base[rb2];
                const float e = blo(u1);   // even frame, center pixel
                {   const uint32_t um = bpermu(am, u0), up = bpermu(ap, u0);
                    crg[0] += e * bhi(um); crg[1] += e * bhi(u0); crg[2] += e * bhi(up); }
                {   const uint32_t um = bpermu(am, u1), up = bpermu(ap, u1);
                    crg[3] += e * bhi(um); crg[4] += e * bhi(u1); crg[5] += e * bhi(up); }
                {   const uint32_t um = bpermu(am, u2), up = bpermu(ap, u2);
                    crg[6] += e * bhi(um); crg[7] += e * bhi(u2); crg[8] += e * bhi(up); }
            }
        }
        // 2-slot reduce: waves 0,1 publish; 2,3 accumulate; wave 0 writes CR
        if (su < 2 && act) {
            #pragma unroll
            for (int ij = 0; ij < 9; ++ij) CP[(su * 9 + ij) * 56 + px] = crg[ij];
        }
        __syncthreads();
        if (su >= 2 && act) {
            const int sl = su - 2;
            #pragma unroll
            for (int ij = 0; ij < 9; ++ij) CP[(sl * 9 + ij) * 56 + px] += crg[ij];
        }
        __syncthreads();
        if (su == 0 && act) {
            #pragma unroll
            for (int ij = 0; ij < 9; ++ij)
                CR[(ij * 8 + g) * 56 + px] =
                    CP[(0 * 9 + ij) * 56 + px] + CP[(1 * 9 + ij) * 56 + px];
        }
        __syncthreads();
    }

    // ---- hoist 36 q-invariant W values (f wave-uniform -> s_loads) ----
    float Wv[9][4];
    #pragma unroll
    for (int ij = 0; ij < 9; ++ij)
        #pragma unroll
        for (int j = 0; j < 4; ++j) {
            const int f = ij * 16 + 4 * su + j;
            const int a = f / 18;
            float w = bconv[f];
            #pragma unroll
            for (int b = 0; b < 9; ++b)
                w += CR[(a * 9 + b) * 56 + px] * wconv[f * 9 + b];
            Wv[ij][j] = w;
        }

    // ================= phase 3: barrier-free weighted gather =================
    float* ob = out + (size_t)n * 256 * HW + r0 * WID;

    #pragma unroll 2
    for (int q = 0; q < 32; ++q) {
        const int ch0 = q * 8 + 2 * su;
        float a0 = 0.f, a1 = 0.f;
        #pragma unroll
        for (int c = 0; c < 2; ++c) {
            const uint32_t* base = xq + (size_t)(ch0 + c) * HW;
            const uint32_t u0 = base[rb0], u1 = base[rb1], u2 = base[rb2];
            float acc = 0.f;
            {   const uint32_t um = bpermu(am, u0), up = bpermu(ap, u0);
                acc += blo(um) * Wv[0][2 * c] + bhi(um) * Wv[0][2 * c + 1];
                acc += blo(u0) * Wv[1][2 * c] + bhi(u0) * Wv[1][2 * c + 1];
                acc += blo(up) * Wv[2][2 * c] + bhi(up) * Wv[2][2 * c + 1]; }
            {   const uint32_t um = bpermu(am, u1), up = bpermu(ap, u1);
                acc += blo(um) * Wv[3][2 * c] + bhi(um) * Wv[3][2 * c + 1];
                acc += blo(u1) * Wv[4][2 * c] + bhi(u1) * Wv[4][2 * c + 1];
                acc += blo(up) * Wv[5][2 * c] + bhi(up) * Wv[5][2 * c + 1]; }
            {   const uint32_t um = bpermu(am, u2), up = bpermu(ap, u2);
                acc += blo(um) * Wv[6][2 * c] + bhi(um) * Wv[6][2 * c + 1];
                acc += blo(u2) * Wv[7][2 * c] + bhi(u2) * Wv[7][2 * c + 1];
                acc += blo(up) * Wv[8][2 * c] + bhi(up) * Wv[8][2 * c + 1]; }
            if (c == 0) a0 = acc; else a1 = acc;
        }
        if (act) {
            ob[(size_t)ch0 * HW + px] = a0;
            ob[(size_t)(ch0 + 1) * HW + px] = a1;
        }
    }
}

// ---------- fallback (ws too small): R13 fp32 kernel, unchanged ----------
__global__ __launch_bounds__(256, 2) void tf_fused_f32(
    const float* __restrict__ x, const float* __restrict__ wconv,
    const float* __restrict__ bconv, float* __restrict__ out)
{
    __shared__ float2 CP[2 * 9 * 28];
    __shared__ float  CR[72 * 56];

    const int d = blockIdx.x;
    const int logical = (d & 7) * 224 + (d >> 3);
    const int n  = logical / 56;
    const int r0 = logical % 56;
    const int t = threadIdx.x;
    const int wv = t >> 6;
    const int l = t & 63;
    const int sub = l >> 5;
    const int s8 = wv * 2 + sub;
    const int qd0 = l & 31;
    const bool act = qd0 < 28;
    const int qd = act ? qd0 : 27;

    const float* xe = x + (size_t)(2 * n) * 256 * HW;
    const float* xo = xe + (size_t)256 * HW;

    const int am = ((qd0 == 0) ? l : (l - 1)) * 4;
    const int ap = ((qd0 >= 27) ? l : (l + 1)) * 4;
    const bool le = (qd0 == 0);
    const bool re = (qd0 >= 27);

    int rb[3];
    #pragma unroll
    for (int di = 0; di < 3; ++di) rb[di] = clampi(r0 + di - 1, 0, 55) * WID + qd * 2;
    const int rc = r0 * WID + qd * 2;

#define MKTAPS2(v, Tm, Tp)                                  \
    {                                                       \
        const float lwp = bperm(am, (v).y);                 \
        const float rwp = bperm(ap, (v).x);                 \
        Tm = make_float2(le ? (v).x : lwp, (v).x);          \
        Tp = make_float2((v).y, re ? (v).y : rwp);          \
    }

    for (int g = 0; g < 8; ++g) {
        const int ch0 = g * 32 + 4 * s8;
        const float* pe = xe + (size_t)ch0 * HW;
        const float* po = xo + (size_t)ch0 * HW;
        float2 crg[9];
        #pragma unroll
        for (int i = 0; i < 9; ++i) crg[i] = make_float2(0.f, 0.f);
        #pragma unroll
        for (int c = 0; c < 4; ++c) {
            const float2 E = *(const float2*)(pe + (size_t)c * HW + rc);
            #pragma unroll
            for (int di = 0; di < 3; ++di) {
                const float2 O = *(const float2*)(po + (size_t)c * HW + rb[di]);
                float2 Tm, Tp;
                MKTAPS2(O, Tm, Tp)
                fma2(crg[di * 3 + 0], E, Tm);
                fma2(crg[di * 3 + 1], E, O);
                fma2(crg[di * 3 + 2], E, Tp);
            }
        }
        #pragma unroll
        for (int ij = 0; ij < 9; ++ij) {
            crg[ij].x += __shfl_xor(crg[ij].x, 32);
            crg[ij].y += __shfl_xor(crg[ij].y, 32);
        }
        if (wv < 2 && sub == 0 && act) {
            #pragma unroll
            for (int ij = 0; ij < 9; ++ij) CP[(wv * 9 + ij) * 28 + qd] = crg[ij];
        }
        __syncthreads();
        if (wv >= 2 && sub == 0 && act) {
            const int sl = wv - 2;
            #pragma unroll
            for (int ij = 0; ij < 9; ++ij) {
                float2 v = CP[(sl * 9 + ij) * 28 + qd];
                v.x += crg[ij].x; v.y += crg[ij].y;
                CP[(sl * 9 + ij) * 28 + qd] = v;
            }
        }
        __syncthreads();
        if (wv == 0 && sub == 0 && act) {
            #pragma unroll
            for (int ij = 0; ij < 9; ++ij) {
                const float2 v0 = CP[(0 * 9 + ij) * 28 + qd];
                const float2 v1 = CP[(1 * 9 + ij) * 28 + qd];
                float2 v;
                v.x = v0.x + v1.x; v.y = v0.y + v1.y;
                *(float2*)(CR + (ij * 8 + g) * 56 + qd * 2) = v;
            }
        }
        __syncthreads();
    }

    float2 We[9], Wo[9];
    #pragma unroll
    for (int ij = 0; ij < 9; ++ij) {
        const int fe = ij * 16 + 2 * s8;
        const int a = fe / 18;
        const float be = bconv[fe], bo = bconv[fe + 1];
        float2 we = make_float2(be, be);
        float2 wo = make_float2(bo, bo);
        #pragma unroll
        for (int b = 0; b < 9; ++b) {
            const float2 c2 = *(const float2*)(CR + (a * 9 + b) * 56 + qd * 2);
            const float wce = wconv[fe * 9 + b];
            const float wco = wconv[fe * 9 + 9 + b];
            we.x += c2.x * wce; we.y += c2.y * wce;
            wo.x += c2.x * wco; wo.y += c2.y * wco;
        }
        We[ij] = we; Wo[ij] = wo;
    }

    float* ob = out + (size_t)n * 256 * HW + r0 * WID + qd * 2;
    #pragma unroll 2
    for (int k = 0; k < 32; ++k) {
        const int ch = k * 8 + s8;
        const float* pe = xe + (size_t)ch * HW;
        const float* po = xo + (size_t)ch * HW;
        float2 acc = make_float2(0.f, 0.f);
        #pragma unroll
        for (int di = 0; di < 3; ++di) {
            const float2 Ev = *(const float2*)(pe + rb[di]);
            const float2 Ov = *(const float2*)(po + rb[di]);
            float2 TEm, TEp, TOm, TOp;
            MKTAPS2(Ev, TEm, TEp)
            MKTAPS2(Ov, TOm, TOp)
            fma2(acc, TEm, We[di * 3 + 0]); fma2(acc, TOm, Wo[di * 3 + 0]);
            fma2(acc, Ev,  We[di * 3 + 1]); fma2(acc, Ov,  Wo[di * 3 + 1]);
            fma2(acc, TEp, We[di * 3 + 2]); fma2(acc, TOp, Wo[di * 3 + 2]);
        }
        if (act) *(float2*)(ob + (size_t)ch * HW) = acc;
    }
#undef MKTAPS2
}

// partial BN stats: block bid -> channel bid>>3, frame-pair slice bid&7 (4 pairs)
__global__ void tf_stats_part(const float* __restrict__ out,
                              float* __restrict__ ps, float* __restrict__ pq)
{
    const int ch = blockIdx.x >> 3;
    const int sl = blockIdx.x & 7;
    const int t = threadIdx.x;

    float s = 0.f, q = 0.f;
    #pragma unroll
    for (int k = 0; k < 4; ++k) {
        const float4* p = (const float4*)(out + ((size_t)(4 * sl + k) * 256 + ch) * HW);
        for (int i = t; i < 784; i += 256) {
            const float4 v = p[i];
            s += v.x + v.y + v.z + v.w;
            q += v.x * v.x + v.y * v.y + v.z * v.z + v.w * v.w;
        }
    }
    #pragma unroll
    for (int o = 32; o >= 1; o >>= 1) {
        s += __shfl_xor(s, o);
        q += __shfl_xor(q, o);
    }
    __shared__ float rs[4], rq[4];
    if ((t & 63) == 0) { rs[t >> 6] = s; rq[t >> 6] = q; }
    __syncthreads();
    if (t == 0) {
        ps[blockIdx.x] = rs[0] + rs[1] + rs[2] + rs[3];
        pq[blockIdx.x] = rq[0] + rq[1] + rq[2] + rq[3];
    }
}

__global__ void tf_stats_fin(const float* __restrict__ ps, const float* __restrict__ pq,
                             const float* __restrict__ gamma, const float* __restrict__ beta,
                             float* __restrict__ AB)
{
    const int ch = threadIdx.x;
    float s = 0.f, q = 0.f;
    #pragma unroll
    for (int sl = 0; sl < 8; ++sl) {
        s += ps[ch * 8 + sl];
        q += pq[ch * 8 + sl];
    }
    const float inv = 1.f / 100352.f;
    const float mean = s * inv;
    const float var = q * inv - mean * mean;
    const float rstd = rsqrtf(var + 1e-5f);
    const float A = gamma[ch] * rstd;
    AB[ch] = A;
    AB[256 + ch] = beta[ch] - mean * A;
}

__global__ void tf_norm(float* __restrict__ out, const float* __restrict__ AB)
{
    const unsigned total4 = 32u * 256u * 784u;
    unsigned i = blockIdx.x * 256u + threadIdx.x;
    const unsigned stride = gridDim.x * 256u;
    float4* o4 = (float4*)out;
    for (; i < total4; i += stride) {
        const unsigned ch = (i / 784u) & 255u;
        const float A = AB[ch], B = AB[256 + ch];
        float4 v = o4[i];
        v.x = v.x * A + B;
        v.y = v.y * A + B;
        v.z = v.z * A + B;
        v.w = v.w * A + B;
        o4[i] = v;
    }
}

extern "C" void kernel_launch(void* const* d_in, const int* in_sizes, int n_in,
                              void* d_out, int out_size, void* d_ws, size_t ws_size,
                              hipStream_t stream) {
    const float* x     = (const float*)d_in[0];
    const float* wconv = (const float*)d_in[1];
    const float* bconv = (const float*)d_in[2];
    const float* gamma = (const float*)d_in[3];
    const float* beta  = (const float*)d_in[4];
    float* out = (float*)d_out;

    float* ps = (float*)d_ws;                    // [2048]
    float* pq = ps + 2048;                       // [2048]
    float* AB = pq + 2048;                       // [512]
    uint32_t* xbuf = (uint32_t*)((uint8_t*)d_ws + 32768);
    const size_t need = 32768 + (size_t)32 * 256 * HW * 4;   // ~102.8 MB

    if (ws_size >= need) {
        tf_pack<<<4096, 256, 0, stream>>>(x, xbuf);
        tf_fused_bf<<<NBLK, 256, 0, stream>>>(xbuf, wconv, bconv, out);
    } else {
        tf_fused_f32<<<NBLK, 256, 0, stream>>>(x, wconv, bconv, out);
    }
    tf_stats_part<<<2048, 256, 0, stream>>>(out, ps, pq);
    tf_stats_fin<<<1, 256, 0, stream>>>(ps, pq, gamma, beta, AB);
    tf_norm<<<2048, 256, 0, stream>>>(out, AB);
}

// Round 15
// 193.318 us; speedup vs baseline: 1.0546x; 1.0546x over previous
//
#include <hip/hip_runtime.h>
#include <cstdint>

#define HW 3136
#define WID 56
#define NBLK 1792   // 32 frame-pairs * 56 rows
#define RSTR 14336  // u32 elements per transposed row-block: 256 ch * 56 col

typedef float f4v __attribute__((ext_vector_type(4)));

__device__ __forceinline__ int clampi(int v, int lo, int hi) {
    return v < lo ? lo : (v > hi ? hi : v);
}
__device__ __forceinline__ uint32_t rne16(float f) {   // fp32 -> bf16 (RNE)
    uint32_t b = __float_as_uint(f);
    return (b + 0x7fffu + ((b >> 16) & 1u)) >> 16;
}
__device__ __forceinline__ float blo(uint32_t u) { return __uint_as_float(u << 16); }
__device__ __forceinline__ float bhi(uint32_t u) { return __uint_as_float(u & 0xffff0000u); }
__device__ __forceinline__ uint32_t bpermu(int a4, uint32_t v) {
    return (uint32_t)__builtin_amdgcn_ds_bpermute(a4, (int)v);
}
__device__ __forceinline__ float bperm(int a4, float v) {
    return __int_as_float(__builtin_amdgcn_ds_bpermute(a4, __float_as_int(v)));
}
__device__ __forceinline__ void fma2(float2& a, const float2& u, const float2& w) {
    a.x += u.x * w.x; a.y += u.y * w.y;
}

// ---------- pass A: stream x (NT loads) -> TRANSPOSED packed bf16 buffer
// xb[pair][row][ch][col], u32 = bf16(even) | bf16(odd)<<16.
// A (pair,row) consumer then sees one contiguous 57-KB block per row.
__global__ __launch_bounds__(256) void tf_pack_t(const float* __restrict__ x,
                                                 uint32_t* __restrict__ xb)
{
    const unsigned total4 = 8192u * 784u;   // (32 pair * 256 ch) planes * 784 quads
    unsigned i = blockIdx.x * 256u + threadIdx.x;
    const unsigned stride = gridDim.x * 256u;
    uint4* xb4 = (uint4*)xb;
    for (; i < total4; i += stride) {
        const unsigned p4 = i / 784u;          // plane = pair*256 + ch
        const unsigned i4 = i - p4 * 784u;     // quad within plane
        const unsigned pair = p4 >> 8;
        const unsigned ch = p4 & 255u;
        const unsigned row = i4 / 14u;         // 14 quads per 56-col row
        const unsigned c4 = i4 - row * 14u;
        const size_t eoff = ((size_t)pair * 512 + ch) * HW + i4 * 4;
        const f4v e = __builtin_nontemporal_load((const f4v*)(x + eoff));
        const f4v o = __builtin_nontemporal_load((const f4v*)(x + eoff + (size_t)256 * HW));
        uint4 u;
        u.x = (rne16(o.x) << 16) | rne16(e.x);
        u.y = (rne16(o.y) << 16) | rne16(e.y);
        u.z = (rne16(o.z) << 16) | rne16(e.z);
        u.w = (rne16(o.w) << 16) | rne16(e.w);
        xb4[(((size_t)pair * 56 + row) * 256 + ch) * 14 + c4] = u;
    }
}

// ---------- pass B: fused corr -> W -> gather on the transposed layout.
// Identical math to R14's tf_fused_bf; only addressing differs (sequential
// 57-KB row-blocks instead of 224-B spans across 512 planes).
__global__ __launch_bounds__(256, 2) void tf_fused_t(
    const uint32_t* __restrict__ xb, const float* __restrict__ wconv,
    const float* __restrict__ bconv, float* __restrict__ out)
{
    __shared__ float CP[2 * 9 * 56];   // 4032 B (2-slot reduce)
    __shared__ float CR[72 * 56];      // 16128 B  -> total 20160 B, 8 blocks/CU

    const int d = blockIdx.x;
    const int logical = (d & 7) * 224 + (d >> 3);   // XCD-contiguous rows
    const int n  = logical / 56;
    const int r0 = logical % 56;
    const int t = threadIdx.x;
    const int su = __builtin_amdgcn_readfirstlane(t >> 6);
    const int lane = t & 63;
    const bool act = lane < WID;
    const int px = act ? lane : 55;

    const uint32_t* xq = xb + (size_t)n * 56 * RSTR;

    const int am = clampi(lane - 1, 0, 55) * 4;   // edge clamp folded in
    const int ap = clampi(lane + 1, 0, 55) * 4;

    const int Rm = clampi(r0 - 1, 0, 55) * RSTR;
    const int Rc = r0 * RSTR;
    const int Rp = clampi(r0 + 1, 0, 55) * RSTR;

    // ================= phase 1: corr -> CR =================
    for (int g = 0; g < 8; ++g) {
        float crg[9];
        #pragma unroll
        for (int i = 0; i < 9; ++i) crg[i] = 0.f;

        #pragma unroll
        for (int sub = 0; sub < 4; ++sub) {
            const int ch0 = (g * 4 + sub) * 8 + 2 * su;
            #pragma unroll
            for (int c = 0; c < 2; ++c) {
                const int co = (ch0 + c) * 56 + px;
                const uint32_t u0 = xq[Rm + co];
                const uint32_t u1 = xq[Rc + co];
                const uint32_t u2 = xq[Rp + co];
                const float e = blo(u1);   // even frame, center pixel
                {   const uint32_t um = bpermu(am, u0), up = bpermu(ap, u0);
                    crg[0] += e * bhi(um); crg[1] += e * bhi(u0); crg[2] += e * bhi(up); }
                {   const uint32_t um = bpermu(am, u1), up = bpermu(ap, u1);
                    crg[3] += e * bhi(um); crg[4] += e * bhi(u1); crg[5] += e * bhi(up); }
                {   const uint32_t um = bpermu(am, u2), up = bpermu(ap, u2);
                    crg[6] += e * bhi(um); crg[7] += e * bhi(u2); crg[8] += e * bhi(up); }
            }
        }
        // 2-slot reduce: waves 0,1 publish; 2,3 accumulate; wave 0 writes CR
        if (su < 2 && act) {
            #pragma unroll
            for (int ij = 0; ij < 9; ++ij) CP[(su * 9 + ij) * 56 + px] = crg[ij];
        }
        __syncthreads();
        if (su >= 2 && act) {
            const int sl = su - 2;
            #pragma unroll
            for (int ij = 0; ij < 9; ++ij) CP[(sl * 9 + ij) * 56 + px] += crg[ij];
        }
        __syncthreads();
        if (su == 0 && act) {
            #pragma unroll
            for (int ij = 0; ij < 9; ++ij)
                CR[(ij * 8 + g) * 56 + px] =
                    CP[(0 * 9 + ij) * 56 + px] + CP[(1 * 9 + ij) * 56 + px];
        }
        __syncthreads();
    }

    // ---- hoist 36 q-invariant W values (f wave-uniform -> s_loads) ----
    float Wv[9][4];
    #pragma unroll
    for (int ij = 0; ij < 9; ++ij)
        #pragma unroll
        for (int j = 0; j < 4; ++j) {
            const int f = ij * 16 + 4 * su + j;
            const int a = f / 18;
            float w = bconv[f];
            #pragma unroll
            for (int b = 0; b < 9; ++b)
                w += CR[(a * 9 + b) * 56 + px] * wconv[f * 9 + b];
            Wv[ij][j] = w;
        }

    // ================= phase 3: barrier-free weighted gather =================
    float* ob = out + (size_t)n * 256 * HW + r0 * WID;

    #pragma unroll 2
    for (int q = 0; q < 32; ++q) {
        const int ch0 = q * 8 + 2 * su;
        float a0 = 0.f, a1 = 0.f;
        #pragma unroll
        for (int c = 0; c < 2; ++c) {
            const int co = (ch0 + c) * 56 + px;
            const uint32_t u0 = xq[Rm + co];
            const uint32_t u1 = xq[Rc + co];
            const uint32_t u2 = xq[Rp + co];
            float acc = 0.f;
            {   const uint32_t um = bpermu(am, u0), up = bpermu(ap, u0);
                acc += blo(um) * Wv[0][2 * c] + bhi(um) * Wv[0][2 * c + 1];
                acc += blo(u0) * Wv[1][2 * c] + bhi(u0) * Wv[1][2 * c + 1];
                acc += blo(up) * Wv[2][2 * c] + bhi(up) * Wv[2][2 * c + 1]; }
            {   const uint32_t um = bpermu(am, u1), up = bpermu(ap, u1);
                acc += blo(um) * Wv[3][2 * c] + bhi(um) * Wv[3][2 * c + 1];
                acc += blo(u1) * Wv[4][2 * c] + bhi(u1) * Wv[4][2 * c + 1];
                acc += blo(up) * Wv[5][2 * c] + bhi(up) * Wv[5][2 * c + 1]; }
            {   const uint32_t um = bpermu(am, u2), up = bpermu(ap, u2);
                acc += blo(um) * Wv[6][2 * c] + bhi(um) * Wv[6][2 * c + 1];
                acc += blo(u2) * Wv[7][2 * c] + bhi(u2) * Wv[7][2 * c + 1];
                acc += blo(up) * Wv[8][2 * c] + bhi(up) * Wv[8][2 * c + 1]; }
            if (c == 0) a0 = acc; else a1 = acc;
        }
        if (act) {
            ob[(size_t)ch0 * HW + px] = a0;
            ob[(size_t)(ch0 + 1) * HW + px] = a1;
        }
    }
}

// ---------- fallback (ws too small): R13 fp32 kernel ----------
__global__ __launch_bounds__(256, 2) void tf_fused_f32(
    const float* __restrict__ x, const float* __restrict__ wconv,
    const float* __restrict__ bconv, float* __restrict__ out)
{
    __shared__ float2 CP[2 * 9 * 28];
    __shared__ float  CR[72 * 56];

    const int d = blockIdx.x;
    const int logical = (d & 7) * 224 + (d >> 3);
    const int n  = logical / 56;
    const int r0 = logical % 56;
    const int t = threadIdx.x;
    const int wv = t >> 6;
    const int l = t & 63;
    const int sub = l >> 5;
    const int s8 = wv * 2 + sub;
    const int qd0 = l & 31;
    const bool act = qd0 < 28;
    const int qd = act ? qd0 : 27;

    const float* xe = x + (size_t)(2 * n) * 256 * HW;
    const float* xo = xe + (size_t)256 * HW;

    const int am = ((qd0 == 0) ? l : (l - 1)) * 4;
    const int ap = ((qd0 >= 27) ? l : (l + 1)) * 4;
    const bool le = (qd0 == 0);
    const bool re = (qd0 >= 27);

    int rb[3];
    #pragma unroll
    for (int di = 0; di < 3; ++di) rb[di] = clampi(r0 + di - 1, 0, 55) * WID + qd * 2;
    const int rc = r0 * WID + qd * 2;

#define MKTAPS2(v, Tm, Tp)                                  \
    {                                                       \
        const float lwp = bperm(am, (v).y);                 \
        const float rwp = bperm(ap, (v).x);                 \
        Tm = make_float2(le ? (v).x : lwp, (v).x);          \
        Tp = make_float2((v).y, re ? (v).y : rwp);          \
    }

    for (int g = 0; g < 8; ++g) {
        const int ch0 = g * 32 + 4 * s8;
        const float* pe = xe + (size_t)ch0 * HW;
        const float* po = xo + (size_t)ch0 * HW;
        float2 crg[9];
        #pragma unroll
        for (int i = 0; i < 9; ++i) crg[i] = make_float2(0.f, 0.f);
        #pragma unroll
        for (int c = 0; c < 4; ++c) {
            const float2 E = *(const float2*)(pe + (size_t)c * HW + rc);
            #pragma unroll
            for (int di = 0; di < 3; ++di) {
                const float2 O = *(const float2*)(po + (size_t)c * HW + rb[di]);
                float2 Tm, Tp;
                MKTAPS2(O, Tm, Tp)
                fma2(crg[di * 3 + 0], E, Tm);
                fma2(crg[di * 3 + 1], E, O);
                fma2(crg[di * 3 + 2], E, Tp);
            }
        }
        #pragma unroll
        for (int ij = 0; ij < 9; ++ij) {
            crg[ij].x += __shfl_xor(crg[ij].x, 32);
            crg[ij].y += __shfl_xor(crg[ij].y, 32);
        }
        if (wv < 2 && sub == 0 && act) {
            #pragma unroll
            for (int ij = 0; ij < 9; ++ij) CP[(wv * 9 + ij) * 28 + qd] = crg[ij];
        }
        __syncthreads();
        if (wv >= 2 && sub == 0 && act) {
            const int sl = wv - 2;
            #pragma unroll
            for (int ij = 0; ij < 9; ++ij) {
                float2 v = CP[(sl * 9 + ij) * 28 + qd];
                v.x += crg[ij].x; v.y += crg[ij].y;
                CP[(sl * 9 + ij) * 28 + qd] = v;
            }
        }
        __syncthreads();
        if (wv == 0 && sub == 0 && act) {
            #pragma unroll
            for (int ij = 0; ij < 9; ++ij) {
                const float2 v0 = CP[(0 * 9 + ij) * 28 + qd];
                const float2 v1 = CP[(1 * 9 + ij) * 28 + qd];
                float2 v;
                v.x = v0.x + v1.x; v.y = v0.y + v1.y;
                *(float2*)(CR + (ij * 8 + g) * 56 + qd * 2) = v;
            }
        }
        __syncthreads();
    }

    float2 We[9], Wo[9];
    #pragma unroll
    for (int ij = 0; ij < 9; ++ij) {
        const int fe = ij * 16 + 2 * s8;
        const int a = fe / 18;
        const float be = bconv[fe], bo = bconv[fe + 1];
        float2 we = make_float2(be, be);
        float2 wo = make_float2(bo, bo);
        #pragma unroll
        for (int b = 0; b < 9; ++b) {
            const float2 c2 = *(const float2*)(CR + (a * 9 + b) * 56 + qd * 2);
            const float wce = wconv[fe * 9 + b];
            const float wco = wconv[fe * 9 + 9 + b];
            we.x += c2.x * wce; we.y += c2.y * wce;
            wo.x += c2.x * wco; wo.y += c2.y * wco;
        }
        We[ij] = we; Wo[ij] = wo;
    }

    float* ob = out + (size_t)n * 256 * HW + r0 * WID + qd * 2;
    #pragma unroll 2
    for (int k = 0; k < 32; ++k) {
        const int ch = k * 8 + s8;
        const float* pe = xe + (size_t)ch * HW;
        const float* po = xo + (size_t)ch * HW;
        float2 acc = make_float2(0.f, 0.f);
        #pragma unroll
        for (int di = 0; di < 3; ++di) {
            const float2 Ev = *(const float2*)(pe + rb[di]);
            const float2 Ov = *(const float2*)(po + rb[di]);
            float2 TEm, TEp, TOm, TOp;
            MKTAPS2(Ev, TEm, TEp)
            MKTAPS2(Ov, TOm, TOp)
            fma2(acc, TEm, We[di * 3 + 0]); fma2(acc, TOm, Wo[di * 3 + 0]);
            fma2(acc, Ev,  We[di * 3 + 1]); fma2(acc, Ov,  Wo[di * 3 + 1]);
            fma2(acc, TEp, We[di * 3 + 2]); fma2(acc, TOp, Wo[di * 3 + 2]);
        }
        if (act) *(float2*)(ob + (size_t)ch * HW) = acc;
    }
#undef MKTAPS2
}

// partial BN stats: block bid -> channel bid>>3, frame-pair slice bid&7 (4 pairs)
__global__ void tf_stats_part(const float* __restrict__ out,
                              float* __restrict__ ps, float* __restrict__ pq)
{
    const int ch = blockIdx.x >> 3;
    const int sl = blockIdx.x & 7;
    const int t = threadIdx.x;

    float s = 0.f, q = 0.f;
    #pragma unroll
    for (int k = 0; k < 4; ++k) {
        const float4* p = (const float4*)(out + ((size_t)(4 * sl + k) * 256 + ch) * HW);
        for (int i = t; i < 784; i += 256) {
            const float4 v = p[i];
            s += v.x + v.y + v.z + v.w;
            q += v.x * v.x + v.y * v.y + v.z * v.z + v.w * v.w;
        }
    }
    #pragma unroll
    for (int o = 32; o >= 1; o >>= 1) {
        s += __shfl_xor(s, o);
        q += __shfl_xor(q, o);
    }
    __shared__ float rs[4], rq[4];
    if ((t & 63) == 0) { rs[t >> 6] = s; rq[t >> 6] = q; }
    __syncthreads();
    if (t == 0) {
        ps[blockIdx.x] = rs[0] + rs[1] + rs[2] + rs[3];
        pq[blockIdx.x] = rq[0] + rq[1] + rq[2] + rq[3];
    }
}

__global__ void tf_stats_fin(const float* __restrict__ ps, const float* __restrict__ pq,
                             const float* __restrict__ gamma, const float* __restrict__ beta,
                             float* __restrict__ AB)
{
    const int ch = threadIdx.x;
    float s = 0.f, q = 0.f;
    #pragma unroll
    for (int sl = 0; sl < 8; ++sl) {
        s += ps[ch * 8 + sl];
        q += pq[ch * 8 + sl];
    }
    const float inv = 1.f / 100352.f;
    const float mean = s * inv;
    const float var = q * inv - mean * mean;
    const float rstd = rsqrtf(var + 1e-5f);
    const float A = gamma[ch] * rstd;
    AB[ch] = A;
    AB[256 + ch] = beta[ch] - mean * A;
}

__global__ void tf_norm(float* __restrict__ out, const float* __restrict__ AB)
{
    const unsigned total4 = 32u * 256u * 784u;
    unsigned i = blockIdx.x * 256u + threadIdx.x;
    const unsigned stride = gridDim.x * 256u;
    float4* o4 = (float4*)out;
    for (; i < total4; i += stride) {
        const unsigned ch = (i / 784u) & 255u;
        const float A = AB[ch], B = AB[256 + ch];
        float4 v = o4[i];
        v.x = v.x * A + B;
        v.y = v.y * A + B;
        v.z = v.z * A + B;
        v.w = v.w * A + B;
        o4[i] = v;
    }
}

extern "C" void kernel_launch(void* const* d_in, const int* in_sizes, int n_in,
                              void* d_out, int out_size, void* d_ws, size_t ws_size,
                              hipStream_t stream) {
    const float* x     = (const float*)d_in[0];
    const float* wconv = (const float*)d_in[1];
    const float* bconv = (const float*)d_in[2];
    const float* gamma = (const float*)d_in[3];
    const float* beta  = (const float*)d_in[4];
    float* out = (float*)d_out;

    float* ps = (float*)d_ws;                    // [2048]
    float* pq = ps + 2048;                       // [2048]
    float* AB = pq + 2048;                       // [512]
    uint32_t* xbuf = (uint32_t*)((uint8_t*)d_ws + 32768);
    const size_t need = 32768 + (size_t)32 * 56 * RSTR * 4;   // ~102.8 MB

    if (ws_size >= need) {
        tf_pack_t<<<4096, 256, 0, stream>>>(x, xbuf);
        tf_fused_t<<<NBLK, 256, 0, stream>>>(xbuf, wconv, bconv, out);
    } else {
        tf_fused_f32<<<NBLK, 256, 0, stream>>>(x, wconv, bconv, out);
    }
    tf_stats_part<<<2048, 256, 0, stream>>>(out, ps, pq);
    tf_stats_fin<<<1, 256, 0, stream>>>(ps, pq, gamma, beta, AB);
    tf_norm<<<2048, 256, 0, stream>>>(out, AB);
}